// Round 8
// baseline (230.792 us; speedup 1.0000x reference)
//
#include <hip/hip_runtime.h>
#include <math.h>

// Closed-form pipeline with Hermitian (real-output) symmetry:
//   Fx  = fft2_128(x)                 (k1 rows pack-2 real trick, k2 cols)
//   k3:  row FFT of 25 psf rows -> FBtmp[img][25][256]
//   k6 fused: per block (img,p) compute FBh rows {p,128-p} IN-KERNEL from
//             FBtmp via Horner DFT (R8: k4 deleted — its rows had exactly
//             one consumer, this block); M=(1-S1)/(S2+b) in regs; FX rows
//             u=p and u=128-p; row IFFT; write Z rows 0..128
//   k7: C2R column IFFT via 128-pt complex FFT fold
// R2: float2 column tiles use width 16 (128 B = bank row) -> conflict-free.
// R3: LDS tiles larger than blockDim need grid-stride loads.
// R4: k4 LDS-issue bound -> registers.
// R5/R6: >128 VGPR live state spills; launch_bounds(256,1) does NOT lift cap.
// R7: standalone k4 stuck at ~59us (stall-bound at 4 waves/SIMD) -> fuse.

static __device__ __forceinline__ float2 cmul(float2 a, float2 b) {
    return make_float2(a.x * b.x - a.y * b.y, a.x * b.y + a.y * b.x);
}
static __device__ __forceinline__ float2 cadd(float2 a, float2 b) {
    return make_float2(a.x + b.x, a.y + b.y);
}
static __device__ __forceinline__ float2 csub(float2 a, float2 b) {
    return make_float2(a.x - b.x, a.y - b.y);
}
static __device__ __forceinline__ float2 conjf2(float2 a) {
    return make_float2(a.x, -a.y);
}

// ---------------- Stockham radix-2 FFT in LDS ----------------
template <int N, int R, int SIGN>
static __device__ __forceinline__ int fft_lds_rows(float2 (&buf)[2][R][N]) {
    constexpr int HB = N / 2;
    const int tid = threadIdx.x;
    const int row = tid / HB;
    const int bt = tid % HB;
    int cur = 0, m = 1, sft = 0;
    for (int l = HB; l >= 1; l >>= 1) {
        __syncthreads();
        const int k = bt & (m - 1);
        const int j = bt >> sft;
        float s, c;
        __sincosf((float)SIGN * (float)M_PI * (float)j / (float)l, &s, &c);
        float2 a = buf[cur][row][bt];
        float2 b = buf[cur][row][bt + HB];
        float2 d = make_float2(a.x - b.x, a.y - b.y);
        float2 wd = make_float2(c * d.x - s * d.y, c * d.y + s * d.x);
        const int o = 2 * bt - k;
        buf[cur ^ 1][row][o] = make_float2(a.x + b.x, a.y + b.y);
        buf[cur ^ 1][row][o + m] = wd;
        cur ^= 1;
        m <<= 1;
        sft++;
    }
    __syncthreads();
    return cur;
}

// Column variant: TC columns (TC=16 -> conflict-free), FFT along axis 0.
template <int N, int TC, int SIGN, int THREADS>
static __device__ __forceinline__ int fft_lds_cols(float2 (&buf)[2][N][TC]) {
    constexpr int HB = N / 2;
    constexpr int WORK = HB * TC;
    const int tid = threadIdx.x;
    int cur = 0, m = 1, sft = 0;
    for (int l = HB; l >= 1; l >>= 1) {
        __syncthreads();
        for (int w = tid; w < WORK; w += THREADS) {
            const int col = w % TC;
            const int bt = w / TC;
            const int k = bt & (m - 1);
            const int j = bt >> sft;
            float s, c;
            __sincosf((float)SIGN * (float)M_PI * (float)j / (float)l, &s, &c);
            float2 a = buf[cur][bt][col];
            float2 b = buf[cur][bt + HB][col];
            float2 d = make_float2(a.x - b.x, a.y - b.y);
            float2 wd = make_float2(c * d.x - s * d.y, c * d.y + s * d.x);
            const int o = 2 * bt - k;
            buf[cur ^ 1][o][col] = make_float2(a.x + b.x, a.y + b.y);
            buf[cur ^ 1][o + m][col] = wd;
        }
        cur ^= 1;
        m <<= 1;
        sft++;
    }
    __syncthreads();
    return cur;
}

// K1: row FFT of x (N=128) with pack-2: rows (2r,2r+1) as re+i*im of one FFT.
__global__ __launch_bounds__(256) void k1_fft_rows_x(const float* __restrict__ x,
                                                     float2* __restrict__ Fx) {
    __shared__ float2 buf[2][4][128];
    const int tid = threadIdx.x;
    const int row = tid >> 6;   // pair slot 0..3
    const int t = tid & 63;
    const int gpair = blockIdx.x * 4 + row;  // img*64 + pr
    const float* r0 = x + (size_t)gpair * 256;        // row 2*pr (128 floats)
    const float* r1 = r0 + 128;                       // row 2*pr+1
    const float2 a0 = ((const float2*)r0)[t];
    const float2 a1 = ((const float2*)r1)[t];
    buf[0][row][2 * t].x = a0.x;
    buf[0][row][2 * t].y = a1.x;
    buf[0][row][2 * t + 1].x = a0.y;
    buf[0][row][2 * t + 1].y = a1.y;
    int cur = fft_lds_rows<128, 4, -1>(buf);
    float2* d0 = Fx + (size_t)gpair * 256;            // Fx row 2*pr
    float2* d1 = d0 + 128;
    for (int h = 0; h < 2; ++h) {
        int tt = t + h * 64;
        float2 Zt = buf[cur][row][tt];
        float2 Zm = buf[cur][row][(128 - tt) & 127];
        d0[tt] = make_float2(0.5f * (Zt.x + Zm.x), 0.5f * (Zt.y - Zm.y));
        float ax = Zt.x - Zm.x, ay = Zt.y + Zm.y;
        d1[tt] = make_float2(0.5f * ay, -0.5f * ax);
    }
}

// K2: column FFT of Fx (N=128), in place. 16 cols/block (conflict-free).
__global__ __launch_bounds__(256) void k2_fft_cols_x(float2* __restrict__ Fx) {
    __shared__ float2 buf[2][128][16];
    const int tid = threadIdx.x;
    const int img = blockIdx.x >> 3;
    const int c0 = (blockIdx.x & 7) * 16;
    float2* base = Fx + (size_t)img * 16384 + c0;
    for (int it = 0; it < 8; ++it) {
        int idx = it * 256 + tid;
        buf[0][idx >> 4][idx & 15] = base[(idx >> 4) * 128 + (idx & 15)];
    }
    int cur = fft_lds_cols<128, 16, -1, 256>(buf);
    for (int it = 0; it < 8; ++it) {
        int idx = it * 256 + tid;
        base[(idx >> 4) * 128 + (idx & 15)] = buf[cur][idx >> 4][idx & 15];
    }
}

// K3: row FFT of padded+rolled psf (N=256), compact output [img][25][256].
__global__ __launch_bounds__(128) void k3_fft_rows_k(const float* __restrict__ kin,
                                                     float2* __restrict__ FBtmp) {
    __shared__ float2 buf[2][1][256];
    const int tid = threadIdx.x;  // 128
    const int img = blockIdx.x / 25;
    const int lr = blockIdx.x % 25;
    const float* krow = kin + img * 625 + lr * 25;
    for (int h = 0; h < 2; ++h) {
        int v = tid + h * 128;
        int pc = (v + 12) & 255;
        buf[0][0][v] = make_float2(pc < 25 ? krow[pc] : 0.f, 0.f);
    }
    int cur = fft_lds_rows<256, 1, -1>(buf);
    float2* dst = FBtmp + (size_t)img * 6400 + lr * 256;
    dst[tid] = buf[cur][0][tid];
    dst[tid + 128] = buf[cur][0][tid + 128];
}

// K6: fused column-DFT + M + FX build + row IFFT.
// Block = (img, p), p=0..64. Stage rows u=p and u=128-p computed in-kernel:
//   FB[u][j] = W^{244u} * P(W^u),  P(z) = sum_q S[q] z^q  (Horner, 25 terms)
// Slot row=0 -> u=p, row=1 -> u=128-p.
__global__ __launch_bounds__(256) void k6_fused(const float2* __restrict__ FBtmp,
                                                const float2* __restrict__ Fx,
                                                const float* __restrict__ alpha,
                                                float2* __restrict__ Z) {
    __shared__ float2 stage[2][256];  // FB rows p and 128-p
    __shared__ float2 buf[2][2][256];
    const int tid = threadIdx.x;
    const int row = tid >> 7;
    const int t = tid & 127;
    const int img = blockIdx.x / 65;
    const int p = blockIdx.x % 65;

    // ---- Phase 1: compute FB rows {p, 128-p} for column j=tid ----
    {
        const float2* src = FBtmp + (size_t)img * 6400 + tid;
        float2 S[25];
#pragma unroll
        for (int q = 0; q < 25; ++q) S[q] = src[q * 256];
        const float k2pi = -2.f * (float)M_PI / 256.f;
#pragma unroll
        for (int h = 0; h < 2; ++h) {
            const int u = h ? (128 - p) : p;
            float sz, cz, sb, cb;
            __sincosf(k2pi * (float)(u & 255), &sz, &cz);
            __sincosf(k2pi * (float)((244 * u) & 255), &sb, &cb);
            float2 z = make_float2(cz, sz);
            float2 acc = S[24];
#pragma unroll
            for (int q = 23; q >= 0; --q) {
                float nx = acc.x * z.x - acc.y * z.y + S[q].x;
                float ny = acc.x * z.y + acc.y * z.x + S[q].y;
                acc.x = nx;
                acc.y = ny;
            }
            stage[h][tid] = make_float2(cb * acc.x - sb * acc.y,
                                        cb * acc.y + sb * acc.x);
        }
    }
    __syncthreads();

    // ---- Phase 2: M + FX + row IFFT (unchanged from R7) ----
    const int u = (row == 0) ? p : (128 - p);   // 0..128
    const int um = u & 127;                     // u==128 -> 0
    const int mi = (um == p) ? 0 : 1;           // stage idx holding row um
    const int oi = 1 - mi;                      // stage idx holding row 128-um

    float2 f00 = stage[mi][t];
    float2 f01 = stage[mi][t + 128];
    float2 f10, f11;
    if (um == 0) {  // rows {0,128}: row 128 direct (only p==0)
        f10 = stage[oi][t];
        f11 = stage[oi][t + 128];
    } else {
        f10 = conjf2(stage[oi][(256 - t) & 255]);
        f11 = conjf2(stage[oi][128 - t]);
    }
    float2 fx = Fx[(size_t)img * 16384 + um * 128 + t];

    float si, ci, sj, cj;
    __sincosf(-(float)M_PI * (float)um / 128.f, &si, &ci);
    __sincosf(-(float)M_PI * (float)t / 128.f, &sj, &cj);
    float2 Di0 = make_float2(1.f + ci, si);
    float2 Di1 = make_float2(1.f - ci, -si);
    float2 Dj0 = make_float2(1.f + cj, sj);
    float2 Dj1 = make_float2(1.f - cj, -sj);
    float2 S1 = cadd(cadd(cmul(cmul(f00, Di0), Dj0), cmul(cmul(f10, Di1), Dj0)),
                     cadd(cmul(cmul(f01, Di0), Dj1), cmul(cmul(f11, Di1), Dj1)));
    S1.x *= 0.25f;
    S1.y *= 0.25f;
    float S2 = 0.25f * (f00.x * f00.x + f00.y * f00.y + f01.x * f01.x + f01.y * f01.y +
                        f10.x * f10.x + f10.y * f10.y + f11.x * f11.x + f11.y * f11.y);
    float b = 1.f / (1.f + __expf(9.f - alpha[img & 63])) + 1e-3f;
    float inv = 1.f / (S2 + b);
    float2 mm = make_float2((1.f - S1.x) * inv, (-S1.y) * inv);

    float2 c0v = (u < 128) ? f00 : f10;
    float2 c1v = (u < 128) ? f01 : f11;
    float2 Du = (u < 128) ? make_float2(1.f + ci, si) : make_float2(1.f - ci, -si);
    float2 Dv0 = make_float2(1.f + cj, sj);
    float2 Dv1 = make_float2(1.f - cj, -sj);
    const float scale = 1.f / 65536.f;
    float2 t0 = cadd(cmul(conjf2(c0v), mm), cmul(Du, Dv0));
    float2 t1 = cadd(cmul(conjf2(c1v), mm), cmul(Du, Dv1));
    float2 FX0 = cmul(fx, t0);
    float2 FX1 = cmul(fx, t1);
    buf[0][row][t] = make_float2(FX0.x * scale, FX0.y * scale);
    buf[0][row][t + 128] = make_float2(FX1.x * scale, FX1.y * scale);
    int cur = fft_lds_rows<256, 2, 1>(buf);
    float2* zb = Z + (size_t)img * 33024 + u * 256;  // p=64: both slots u=64, same data
    zb[t] = buf[cur][row][t];
    zb[t + 128] = buf[cur][row][t + 128];
}

// K7: C2R column IFFT, 16 cols/block. Fold rows 0..128 -> 128-pt complex IFFT.
__global__ __launch_bounds__(256) void k7_c2r(const float2* __restrict__ Z,
                                              float* __restrict__ out) {
    __shared__ float2 S[129][16];
    __shared__ float2 buf[2][128][16];
    const int tid = threadIdx.x;
    const int img = blockIdx.x >> 4;
    const int c0 = (blockIdx.x & 15) * 16;
    const float2* zb = Z + (size_t)img * 33024 + c0;
    for (int idx = tid; idx < 129 * 16; idx += 256) {
        int r = idx >> 4, c = idx & 15;
        S[r][c] = zb[r * 256 + c];
    }
    __syncthreads();
    for (int idx = tid; idx < 128 * 16; idx += 256) {
        int u = idx >> 4, c = idx & 15;
        float2 su = S[u][c];
        float2 s2 = conjf2(S[128 - u][c]);
        float2 e = cadd(su, s2);
        float2 o = csub(su, s2);
        float ws_, wc_;
        __sincosf((float)M_PI * (float)u / 128.f, &ws_, &wc_);
        float2 wo = make_float2(wc_ * o.x - ws_ * o.y, wc_ * o.y + ws_ * o.x);
        buf[0][u][c] = make_float2(e.x - wo.y, e.y + wo.x);  // e + i*wo
    }
    int cur = fft_lds_cols<128, 16, 1, 256>(buf);
    float* ob = out + (size_t)img * 65536 + c0;
    for (int idx = tid; idx < 128 * 16; idx += 256) {
        int n = idx >> 4, c = idx & 15;
        float2 y = buf[cur][n][c];
        ob[(2 * n) * 256 + c] = y.x;
        ob[(2 * n + 1) * 256 + c] = y.y;
    }
}

extern "C" void kernel_launch(void* const* d_in, const int* in_sizes, int n_in,
                              void* d_out, int out_size, void* d_ws, size_t ws_size,
                              hipStream_t stream) {
    const float* x = (const float*)d_in[0];      // (4,64,128,128)
    const float* k = (const float*)d_in[1];      // (4,64,25,25)
    const float* alpha = (const float*)d_in[2];  // (1,64,1,1)
    float* out = (float*)d_out;                  // (4,64,256,256)

    float2* Fx = (float2*)d_ws;           // 256*16384   = 32 MB
    float2* Z = Fx + 256 * 16384;         // 256*129*256 = 67.6 MB
    float2* FBtmp = Z + 256 * 33024;      // 256*25*256  = 13.1 MB

    hipLaunchKernelGGL(k1_fft_rows_x, dim3(4096), dim3(256), 0, stream, x, Fx);
    hipLaunchKernelGGL(k2_fft_cols_x, dim3(2048), dim3(256), 0, stream, Fx);
    hipLaunchKernelGGL(k3_fft_rows_k, dim3(6400), dim3(128), 0, stream, k, FBtmp);
    hipLaunchKernelGGL(k6_fused, dim3(256 * 65), dim3(256), 0, stream, FBtmp, Fx, alpha, Z);
    hipLaunchKernelGGL(k7_c2r, dim3(4096), dim3(256), 0, stream, Z, out);
}